// Round 6
// baseline (197.293 us; speedup 1.0000x reference)
//
#include <hip/hip_runtime.h>
#include <stdint.h>

// Problem constants
#define K_DIM   2048      // IN_DIM
#define NN      2047      // N_NODES
#define NPAD    2048      // padded node dim
#define BATCH   16384
#define ODIM    10
#define IOFF    (128 * 2048)   // +128 rows (A) / +128 cols (B) in elements

typedef __attribute__((ext_vector_type(8))) short   bf16x8;
typedef __attribute__((ext_vector_type(16))) float  f32x16;

static __device__ __forceinline__ unsigned short f2bf(float f) {
    union { float f; unsigned int u; } c; c.f = f;
    unsigned int u = c.u;
    return (unsigned short)((u + 0x7fffu + ((u >> 16) & 1u)) >> 16);
}
static __device__ __forceinline__ float bf2f(unsigned short h) {
    union { unsigned int u; float f; } c; c.u = ((unsigned int)h) << 16;
    return c.f;
}

// ---------------- fused fp32 -> bf16 conversion: in_x and padded W1 ----------------
__global__ __launch_bounds__(256) void cvt_all(const float* __restrict__ xs,
                                               const float* __restrict__ ws,
                                               unsigned short* __restrict__ dx,
                                               unsigned short* __restrict__ dw) {
    int b = blockIdx.x;
    union { unsigned short h[8]; uint4 v; } o;
    if (b < 16384) {
        int i = b * 256 + threadIdx.x;
        const float4* s = (const float4*)xs + (size_t)i * 2;
        float4 a = s[0], c = s[1];
        o.h[0] = f2bf(a.x); o.h[1] = f2bf(a.y); o.h[2] = f2bf(a.z); o.h[3] = f2bf(a.w);
        o.h[4] = f2bf(c.x); o.h[5] = f2bf(c.y); o.h[6] = f2bf(c.z); o.h[7] = f2bf(c.w);
        *((uint4*)dx + i) = o.v;
    } else {
        int i = (b - 16384) * 256 + threadIdx.x;
        size_t e = (size_t)i * 8;
        int row = (int)(e >> 11);
        if (row < NN) {
            const float4* s = (const float4*)(ws + e);
            float4 a = s[0], c = s[1];
            o.h[0] = f2bf(a.x); o.h[1] = f2bf(a.y); o.h[2] = f2bf(a.z); o.h[3] = f2bf(a.w);
            o.h[4] = f2bf(c.x); o.h[5] = f2bf(c.y); o.h[6] = f2bf(c.z); o.h[7] = f2bf(c.w);
        } else {
            o.v = make_uint4(0u, 0u, 0u, 0u);
        }
        *((uint4*)dw + i) = o.v;
    }
}

// ---------------- 256x256 bf16 GEMM, 8 waves, 32x32x16 MFMA, full read-ahead ----------------
// Every ds_read >=1 window before its MFMA; every stage exactly 6 windows before its read;
// uniform VM10 at window ends (each drains exactly one stage-pair). Swizzle swz(r) =
// (r&7) ^ (((r>>3)&3)<<1) applied on staging source granule AND read col (conflict-free at
// 8-consecutive, stride-8, and quarter-wave lane groupings).
__global__ __launch_bounds__(512, 2) void gemm32(const unsigned short* __restrict__ A,
                                                 const unsigned short* __restrict__ B,
                                                 const float* __restrict__ bias,
                                                 unsigned short* __restrict__ X) {
    __shared__ char lds[131072];   // 2 buf x {A0,A1,B0,B1} x 16KiB

    const int t0   = threadIdx.x;
    const int w    = t0 >> 6;
    const int lane = t0 & 63;
    const int wm = w >> 2, wn = w & 3;     // wave -> 128 rows x 64 cols
    const int lr5 = lane & 31, hi5 = lane >> 5;
    const int xm5 = (((lr5 & 7) ^ (((lr5 >> 3) & 3) << 1)) << 4);   // read-side swizzle

    // XCD-aware swizzle: 512 wgs, 64 per XCD
    int bid = blockIdx.x;
    int swz = (bid & 7) * 64 + (bid >> 3);
    const int rowBase = (swz >> 3) * 256;  // 64 row-tiles
    const int colBase = (swz & 7) * 256;   // 8 col-tiles

    // staging source pointers (pre-swizzled global addresses)
    const int li = lane >> 3;   // row-within-8
    const int lg = lane & 7;    // 16B granule
    const unsigned short* sA[2];
    const unsigned short* sB[2];
    {
        int rho = w * 8 + li;                              // 0..63
        int gc  = (lg ^ li ^ ((w & 3) << 1)) * 8;          // swizzled k-granule
#pragma unroll
        for (int h = 0; h < 2; ++h) {
            sA[h] = A + (size_t)(rowBase + h * 64 + rho) * K_DIM + gc;
            sB[h] = B + (size_t)(colBase + (rho >> 5) * 64 + h * 32 + (rho & 31)) * K_DIM + gc;
        }
    }

#define AS1 __attribute__((address_space(1)))
#define AS3 __attribute__((address_space(3)))
#define STAGE_(src, dstoff) \
    __builtin_amdgcn_global_load_lds((const AS1 void*)(src), \
        (AS3 void*)(lds + (dstoff) + w * 1024), 16, 0, 0)
#define STAGE_A(hh, kt, p) do { const unsigned short* _s = sA[hh] + (kt) * 64; \
    const int _d = (p) * 65536 + (hh) * 16384; \
    STAGE_(_s, _d); STAGE_(_s + IOFF, _d + 8192); } while (0)
#define STAGE_B(gg, kt, p) do { const unsigned short* _s = sB[gg] + (kt) * 64; \
    const int _d = (p) * 65536 + 32768 + (gg) * 16384; \
    STAGE_(_s, _d); STAGE_(_s + IOFF, _d + 8192); } while (0)

    // 32x32x16 fragment reads. A: row = wm half (8KB) + mb*32 + lr5.
#define LDSA32(bo, half, mb, ks) (*(const bf16x8*)(lds + (bo) + (half) * 16384 + wm * 8192 + \
        ((mb) * 32 + lr5) * 128 + (((ks) * 32 + hi5 * 16) ^ xm5)))
    // B: col = wn*64 + hb*32 + lr5 -> region hb, sub-block wn>>1, row (wn&1)*32+lr5.
#define LDSB32(bo, hb, ks) (*(const bf16x8*)(lds + (bo) + 32768 + (hb) * 16384 + (wn >> 1) * 8192 + \
        ((wn & 1) * 32 + lr5) * 128 + (((ks) * 32 + hi5 * 16) ^ xm5)))

#define BAR()   __builtin_amdgcn_s_barrier()
#define SB0()   __builtin_amdgcn_sched_barrier(0)
#define VM8()   asm volatile("s_waitcnt vmcnt(8)" ::: "memory")
#define VM10()  asm volatile("s_waitcnt vmcnt(10)" ::: "memory")
#define PRIO1() __builtin_amdgcn_s_setprio(1)
#define PRIO0() __builtin_amdgcn_s_setprio(0)

    f32x16 acc[2][2][2];   // [half][mb][hb]
#pragma unroll
    for (int h = 0; h < 2; ++h)
#pragma unroll
        for (int m = 0; m < 2; ++m)
#pragma unroll
            for (int n = 0; n < 2; ++n) acc[h][m][n] = (f32x16)0.f;

    // Fixed-role fragment sets (no rotation): aA0/aA1 = A halves, bB0/bB1 = B halves.
    bf16x8 aA0[2][4], aA1[2][4], bB0[4], bB1[4];

#define RD_A32(dst, bo, half) do { \
    _Pragma("unroll") for (int mb = 0; mb < 2; ++mb) \
    _Pragma("unroll") for (int ks = 0; ks < 4; ++ks) dst[mb][ks] = LDSA32(bo, half, mb, ks); } while (0)
#define RD_B32(dst, bo, hb) do { \
    _Pragma("unroll") for (int ks = 0; ks < 4; ++ks) dst[ks] = LDSB32(bo, hb, ks); } while (0)

#define CL32(HALF, HB, AF, BF) do { \
    _Pragma("unroll") for (int mb = 0; mb < 2; ++mb) \
    _Pragma("unroll") for (int ks = 0; ks < 4; ++ks) \
        acc[HALF][mb][HB] = __builtin_amdgcn_mfma_f32_32x32x16_bf16( \
            AF[mb][ks], BF[ks], acc[HALF][mb][HB], 0, 0, 0); } while (0)

    // ---- prologue: virtual tiles -2,-1 in per-tile stage order {A0,B0,B1,A1} ----
    STAGE_A(0, 0, 0); STAGE_B(0, 0, 0); STAGE_B(1, 0, 0); STAGE_A(1, 0, 0);   // tile0 -> buf0
    STAGE_A(0, 1, 1); STAGE_B(0, 1, 1); STAGE_B(1, 1, 1); STAGE_A(1, 1, 1);   // tile1 -> buf1
    VM8(); BAR();                     // drain tile0's 4 pairs; tile1's 4 remain in flight
    RD_A32(aA0, 0, 0);                // A0(0)
    RD_B32(bB0, 0, 0);                // B0(0)

    // Steady state per tile T (bo = T&1 buffer, bp = other):
    //  W1: rd B1(T) [bo];  stage A0(T+2)->bo;  C1 = aA0 x bB0;  VM10; BAR
    //  W2: rd A1(T) [bo];  stage B0(T+2)->bo;  C2 = aA0 x bB1;  VM10; BAR
    //  W3: rd A0(T+1)[bp]; stage B1(T+2)->bo;  C3 = aA1 x bB1;  VM10; BAR
    //  W4:                 stage A1(T+2)->bo;  C4 = aA1 x bB0;  rd B0(T+1)[bp]; VM10; BAR
    // Every stage->read gap = 6 windows; VM10 drains exactly the pair read next window.
#define TILE(T, PAR) do { \
    const int _bo = (PAR) * 65536, _bp = ((PAR) ^ 1) * 65536; \
    const int _k2 = ((T) + 2) & 31; \
    RD_B32(bB1, _bo, 1); STAGE_A(0, _k2, (PAR)); \
    SB0(); PRIO1(); CL32(0, 0, aA0, bB0); PRIO0(); VM10(); BAR(); \
    RD_A32(aA1, _bo, 1); STAGE_B(0, _k2, (PAR)); \
    SB0(); PRIO1(); CL32(0, 1, aA0, bB1); PRIO0(); VM10(); BAR(); \
    RD_A32(aA0, _bp, 0); STAGE_B(1, _k2, (PAR)); \
    SB0(); PRIO1(); CL32(1, 1, aA1, bB1); PRIO0(); VM10(); BAR(); \
    STAGE_A(1, _k2, (PAR)); \
    SB0(); PRIO1(); CL32(1, 0, aA1, bB0); PRIO0(); RD_B32(bB0, _bp, 0); VM10(); BAR(); \
} while (0)

#pragma unroll 1
    for (int tp = 0; tp < 16; ++tp) {
        TILE(tp * 2,     0);
        TILE(tp * 2 + 1, 1);
    }

    // ---- epilogue: + bias, store bf16. C/D: col=lane&31, row=(reg&3)+8*(reg>>2)+4*hi5 ----
    float bb[2];
#pragma unroll
    for (int hb = 0; hb < 2; ++hb) {
        int col = colBase + wn * 64 + hb * 32 + lr5;
        bb[hb] = (col < NN) ? bias[col] : 0.f;
    }
#pragma unroll
    for (int half = 0; half < 2; ++half)
#pragma unroll
        for (int mb = 0; mb < 2; ++mb)
#pragma unroll
            for (int hb = 0; hb < 2; ++hb) {
                int colb = colBase + wn * 64 + hb * 32 + lr5;
#pragma unroll
                for (int reg = 0; reg < 16; ++reg) {
                    int roff = (reg & 3) + 8 * (reg >> 2) + 4 * hi5;
                    int row = rowBase + wm * 128 + half * 64 + mb * 32 + roff;
                    X[(size_t)row * NPAD + colb] = f2bf(acc[half][mb][hb][reg] + bb[hb]);
                }
            }
}

// ---------------- tree kernel: out[b,a] = S_abs[b] - min_{leaf≡a mod 10} pathPenalty ----------------
__global__ __launch_bounds__(256) void tree_kernel(const unsigned short* __restrict__ X,
                                                   float* __restrict__ out) {
    __shared__ float xs[4][2048];
    __shared__ float cm[4][64][ODIM];
    const int w    = threadIdx.x >> 6;
    const int lane = threadIdx.x & 63;
    const int row  = blockIdx.x * 4 + w;
    const unsigned short* xr = X + (size_t)row * NPAD;

#pragma unroll
    for (int i = 0; i < 4; ++i) {
        int base = i * 512 + lane * 8;
        uint4 v = *(const uint4*)(xr + base);
        const unsigned short* h = (const unsigned short*)&v;
#pragma unroll
        for (int j = 0; j < 8; ++j) xs[w][base + j] = bf2f(h[j]);
    }
    __syncthreads();

    float sabs = 0.f;
#pragma unroll
    for (int i = 0; i < 32; ++i) sabs += fabsf(xs[w][lane + i * 64]);
#pragma unroll
    for (int d = 1; d < 64; d <<= 1) sabs += __shfl_xor(sabs, d, 64);

    const int L = lane;
    float bp = 0.f;
#pragma unroll
    for (int l = 0; l <= 5; ++l) {
        float v = xs[w][(1 << l) - 1 + (L >> (6 - l))];
        bp += ((L >> (5 - l)) & 1) ? fmaxf(v, 0.f) : fmaxf(-v, 0.f);
    }
    float p2[2], p4[4], p8[8], p16[16], p32[32];
    {
        float v = xs[w][63 + L];
        p2[0] = bp + fmaxf(-v, 0.f);
        p2[1] = bp + fmaxf(v, 0.f);
    }
#pragma unroll
    for (int c = 0; c < 2; ++c) {
        float v = xs[w][127 + 2 * L + c];
        p4[2 * c]     = p2[c] + fmaxf(-v, 0.f);
        p4[2 * c + 1] = p2[c] + fmaxf(v, 0.f);
    }
#pragma unroll
    for (int c = 0; c < 4; ++c) {
        float v = xs[w][255 + 4 * L + c];
        p8[2 * c]     = p4[c] + fmaxf(-v, 0.f);
        p8[2 * c + 1] = p4[c] + fmaxf(v, 0.f);
    }
#pragma unroll
    for (int c = 0; c < 8; ++c) {
        float v = xs[w][511 + 8 * L + c];
        p16[2 * c]     = p8[c] + fmaxf(-v, 0.f);
        p16[2 * c + 1] = p8[c] + fmaxf(v, 0.f);
    }
#pragma unroll
    for (int c = 0; c < 16; ++c) {
        float v = xs[w][1023 + 16 * L + c];
        p32[2 * c]     = p16[c] + fmaxf(-v, 0.f);
        p32[2 * c + 1] = p16[c] + fmaxf(v, 0.f);
    }

    float m[ODIM];
#pragma unroll
    for (int r = 0; r < ODIM; ++r) m[r] = 1e30f;
#pragma unroll
    for (int tt = 0; tt < 32; ++tt) m[tt % ODIM] = fminf(m[tt % ODIM], p32[tt]);

    int base_mod = (L * 32) % ODIM;
#pragma unroll
    for (int r = 0; r < ODIM; ++r) {
        int a = base_mod + r; if (a >= ODIM) a -= ODIM;
        cm[w][L][a] = m[r];
    }
    __syncthreads();

    if (lane < ODIM) {
        float mn = 1e30f;
        for (int l2 = 0; l2 < 64; ++l2) mn = fminf(mn, cm[w][l2][lane]);
        out[(size_t)row * ODIM + lane] = sabs - mn;
    }
}

extern "C" void kernel_launch(void* const* d_in, const int* in_sizes, int n_in,
                              void* d_out, int out_size, void* d_ws, size_t ws_size,
                              hipStream_t stream) {
    const float* in_x = (const float*)d_in[0];
    const float* W1   = (const float*)d_in[1];
    const float* b1   = (const float*)d_in[2];

    unsigned short* Abf = (unsigned short*)d_ws;                      // 16384*2048 bf16
    unsigned short* Wbf = Abf + (size_t)BATCH * K_DIM;                // 2048*2048 bf16
    unsigned short* Xbf = Wbf + (size_t)NPAD * K_DIM;                 // 16384*2048 bf16
    float* out = (float*)d_out;

    cvt_all<<<18432, 256, 0, stream>>>(in_x, W1, Abf, Wbf);
    gemm32<<<512, 512, 0, stream>>>(Abf, Wbf, b1, Xbf);
    tree_kernel<<<BATCH / 4, 256, 0, stream>>>(Xbf, out);
}

// Round 7
// 184.078 us; speedup vs baseline: 1.0718x; 1.0718x over previous
//
#include <hip/hip_runtime.h>
#include <stdint.h>

// Problem constants
#define K_DIM   2048      // IN_DIM
#define NN      2047      // N_NODES
#define NPAD    2048      // padded node dim
#define BATCH   16384
#define ODIM    10
#define IOFF    (128 * 2048)   // +128 rows (A) / +128 cols (B) in elements

typedef __attribute__((ext_vector_type(8))) short  bf16x8;
typedef __attribute__((ext_vector_type(4))) float  f32x4;

static __device__ __forceinline__ unsigned short f2bf(float f) {
    union { float f; unsigned int u; } c; c.f = f;
    unsigned int u = c.u;
    return (unsigned short)((u + 0x7fffu + ((u >> 16) & 1u)) >> 16);
}
static __device__ __forceinline__ float bf2f(unsigned short h) {
    union { unsigned int u; float f; } c; c.u = ((unsigned int)h) << 16;
    return c.f;
}

// ---------------- fused fp32 -> bf16 conversion: in_x and padded W1 ----------------
__global__ __launch_bounds__(256) void cvt_all(const float* __restrict__ xs,
                                               const float* __restrict__ ws,
                                               unsigned short* __restrict__ dx,
                                               unsigned short* __restrict__ dw) {
    int b = blockIdx.x;
    union { unsigned short h[8]; uint4 v; } o;
    if (b < 16384) {
        int i = b * 256 + threadIdx.x;
        const float4* s = (const float4*)xs + (size_t)i * 2;
        float4 a = s[0], c = s[1];
        o.h[0] = f2bf(a.x); o.h[1] = f2bf(a.y); o.h[2] = f2bf(a.z); o.h[3] = f2bf(a.w);
        o.h[4] = f2bf(c.x); o.h[5] = f2bf(c.y); o.h[6] = f2bf(c.z); o.h[7] = f2bf(c.w);
        *((uint4*)dx + i) = o.v;
    } else {
        int i = (b - 16384) * 256 + threadIdx.x;
        size_t e = (size_t)i * 8;
        int row = (int)(e >> 11);
        if (row < NN) {
            const float4* s = (const float4*)(ws + e);
            float4 a = s[0], c = s[1];
            o.h[0] = f2bf(a.x); o.h[1] = f2bf(a.y); o.h[2] = f2bf(a.z); o.h[3] = f2bf(a.w);
            o.h[4] = f2bf(c.x); o.h[5] = f2bf(c.y); o.h[6] = f2bf(c.z); o.h[7] = f2bf(c.w);
        } else {
            o.v = make_uint4(0u, 0u, 0u, 0u);
        }
        *((uint4*)dw + i) = o.v;
    }
}

// ---------------- 256x256 bf16 MFMA GEMM: X = A @ W^T + bias (R3 base, merged phases) ----------------
// Per phase: [stage | ds_reads | MFMA x16] in ONE region (compiler emits counted lgkmcnt,
// reads interleave with MFMA), then counted VM, then single barrier. 16x16x32 MFMA
// (0-conflict read pattern). Stage/VM chronology identical to R3.
__global__ __launch_bounds__(512, 1) void gemm8(const unsigned short* __restrict__ A,
                                                const unsigned short* __restrict__ B,
                                                const float* __restrict__ bias,
                                                unsigned short* __restrict__ X) {
    __shared__ char lds[131072];   // 2 buf x {A0,A1,B0,B1} x 16KiB

    const int t0   = threadIdx.x;
    const int w    = t0 >> 6;
    const int lane = t0 & 63;
    const int wm = w >> 2, wn = w & 3;     // wave -> 128x64 output block
    const int lr = lane & 15, lk = lane >> 4;
    const int xmask = (lr & 7) << 4;       // read-side swizzle

    // XCD-aware swizzle: 512 wgs, 64 per XCD
    int bid = blockIdx.x;
    int swz = (bid & 7) * 64 + (bid >> 3);
    const int rowBase = (swz >> 3) * 256;  // 64 row-tiles
    const int colBase = (swz & 7) * 256;   // 8 col-tiles

    // staging source pointers (pre-swizzled global addresses); i=1 = +IOFF elems
    const int li = lane >> 3;   // row-within-8
    const int lg = lane & 7;    // 16B granule
    const unsigned short* sA[2];
    const unsigned short* sB[2];
    {
        int rho = w * 8 + li;                              // 0..63
        int gc  = (lg ^ (rho & 7)) * 8;                    // swizzled k-granule
#pragma unroll
        for (int h = 0; h < 2; ++h) {
            sA[h] = A + (size_t)(rowBase + h * 64 + rho) * K_DIM + gc;
            sB[h] = B + (size_t)(colBase + (rho >> 5) * 64 + h * 32 + (rho & 31)) * K_DIM + gc;
        }
    }

#define AS1 __attribute__((address_space(1)))
#define AS3 __attribute__((address_space(3)))
#define STAGE_(src, dstoff) \
    __builtin_amdgcn_global_load_lds((const AS1 void*)(src), \
        (AS3 void*)(lds + (dstoff) + w * 1024), 16, 0, 0)
#define STAGE_A(hh, kt, p) do { const unsigned short* _s = sA[hh] + (kt) * 64; \
    const int _d = (p) * 65536 + (hh) * 16384; \
    STAGE_(_s, _d); STAGE_(_s + IOFF, _d + 8192); } while (0)
#define STAGE_B(gg, kt, p) do { const unsigned short* _s = sB[gg] + (kt) * 64; \
    const int _d = (p) * 65536 + 32768 + (gg) * 16384; \
    STAGE_(_s, _d); STAGE_(_s + IOFF, _d + 8192); } while (0)

#define LDSA(bo, hh, mm, ks) (*(const bf16x8*)(lds + (bo) + (hh) * 16384 + \
        (wm * 64 + (mm) * 16 + lr) * 128 + (((ks) * 64 + lk * 16) ^ xmask)))
#define LDSB(bo, gg, nn, ks) (*(const bf16x8*)(lds + (bo) + 32768 + (gg) * 16384 + \
        (wn * 32 + (nn) * 16 + lr) * 128 + (((ks) * 64 + lk * 16) ^ xmask)))

#define BAR()   __builtin_amdgcn_s_barrier()
#define VM8()   asm volatile("s_waitcnt vmcnt(8)" ::: "memory")
#define VM10()  asm volatile("s_waitcnt vmcnt(10)" ::: "memory")
#define PRIO1() __builtin_amdgcn_s_setprio(1)
#define PRIO0() __builtin_amdgcn_s_setprio(0)

    f32x4 acc[8][4];
#pragma unroll
    for (int m = 0; m < 8; ++m)
#pragma unroll
        for (int n = 0; n < 4; ++n) acc[m][n] = (f32x4)0.f;

    bf16x8 aF[4][2], bF1[2][2], bF0a[2][2], bF0b[2][2];

#define RD8A(bo, hh) do { \
    _Pragma("unroll") for (int m = 0; m < 4; ++m) { \
        aF[m][0] = LDSA(bo, hh, m, 0); aF[m][1] = LDSA(bo, hh, m, 1); } } while (0)
#define RD4B(dst, bo, gg) do { \
    _Pragma("unroll") for (int n = 0; n < 2; ++n) { \
        dst[n][0] = LDSB(bo, gg, n, 0); dst[n][1] = LDSB(bo, gg, n, 1); } } while (0)

#define MFMA8(MB, NB, BF) do { \
    _Pragma("unroll") for (int m = 0; m < 4; ++m) \
    _Pragma("unroll") for (int n = 0; n < 2; ++n) \
    _Pragma("unroll") for (int ks = 0; ks < 2; ++ks) \
        acc[(MB) + m][(NB) + n] = __builtin_amdgcn_mfma_f32_16x16x32_bf16( \
            aF[m][ks], BF[n][ks], acc[(MB) + m][(NB) + n], 0, 0, 0); } while (0)

    // ---- prologue: tile0 full + tile1 {A0,B0,B1,A1} = 8 stage-pairs ----
    STAGE_A(0, 0, 0); STAGE_A(1, 0, 0); STAGE_B(0, 0, 0); STAGE_B(1, 0, 0);
    STAGE_A(0, 1, 1); STAGE_B(0, 1, 1); STAGE_B(1, 1, 1); STAGE_A(1, 1, 1);
    VM8(); BAR();                     // drains tile0's 4 pairs (incl. B1(0))
    RD4B(bF0a, 0, 0);                 // pre-read B0(tile0) from buf0

    // Stage schedule: P1 stages A1(T+1); P2/P3/P4 stage A0/B0/B1(T+2).
    // Guards (issue-order accounting): P2-end VM10, P3-end VM8, P4-end VM8 —
    // each region drained >=1 window before its (post-BAR) read.
#define TILE(T, PAR, CUR, NXT) do { \
    const int _bo = (PAR) * 65536, _bp = ((PAR) ^ 1) * 65536; \
    const int _k1 = ((T) + 1) & 31, _k2 = ((T) + 2) & 31; \
    /* P1: stage A1(T+1); read A0(T); C1 = A0 x B0 (reads || MFMA, counted lgkm) */ \
    STAGE_A(1, _k1, (PAR) ^ 1); \
    RD8A(_bo, 0); \
    PRIO1(); MFMA8(0, 0, CUR); PRIO0(); BAR(); \
    /* P2: stage A0(T+2); read B1(T); C2 = A0 x B1 */ \
    STAGE_A(0, _k2, (PAR)); \
    RD4B(bF1, _bo, 1); \
    PRIO1(); MFMA8(0, 2, bF1); PRIO0(); VM10(); BAR(); \
    /* P3: stage B0(T+2); read A1(T); C3 = A1 x B1 */ \
    STAGE_B(0, _k2, (PAR)); \
    RD8A(_bo, 1); \
    PRIO1(); MFMA8(4, 2, bF1); PRIO0(); VM8(); BAR(); \
    /* P4: stage B1(T+2); read B0(T+1)->NXT; C4 = A1 x B0 (no lgkm dep on MFMA) */ \
    STAGE_B(1, _k2, (PAR)); \
    RD4B(NXT, _bp, 0); \
    PRIO1(); MFMA8(4, 0, CUR); PRIO0(); VM8(); BAR(); \
} while (0)

#pragma unroll 1
    for (int tp = 0; tp < 16; ++tp) {
        TILE(tp * 2,     0, bF0a, bF0b);
        TILE(tp * 2 + 1, 1, bF0b, bF0a);
    }

    // ---- epilogue: + bias, store bf16. C/D: col = lane&15, row = (lane>>4)*4 + reg ----
    float bb[4];
#pragma unroll
    for (int ni = 0; ni < 4; ++ni) {
        int col = colBase + wn * 64 + (ni >> 1) * 32 + (ni & 1) * 16 + lr;
        bb[ni] = (col < NN) ? bias[col] : 0.f;
    }
#pragma unroll
    for (int mi = 0; mi < 8; ++mi) {
        int row = rowBase + wm * 128 + (mi >> 2) * 64 + (mi & 3) * 16 + lk * 4;
#pragma unroll
        for (int j = 0; j < 4; ++j) {
            unsigned short* xr = X + (size_t)(row + j) * NPAD + colBase + wn * 64 + lr;
#pragma unroll
            for (int ni = 0; ni < 4; ++ni)
                xr[(ni >> 1) * 32 + (ni & 1) * 16] = f2bf(acc[mi][ni][j] + bb[ni]);
        }
    }
}

// ---------------- tree kernel: out[b,a] = S_abs[b] - min_{leaf≡a mod 10} pathPenalty ----------------
__global__ __launch_bounds__(256) void tree_kernel(const unsigned short* __restrict__ X,
                                                   float* __restrict__ out) {
    __shared__ float xs[4][2048];
    __shared__ float cm[4][64][ODIM];
    const int w    = threadIdx.x >> 6;
    const int lane = threadIdx.x & 63;
    const int row  = blockIdx.x * 4 + w;
    const unsigned short* xr = X + (size_t)row * NPAD;

#pragma unroll
    for (int i = 0; i < 4; ++i) {
        int base = i * 512 + lane * 8;
        uint4 v = *(const uint4*)(xr + base);
        const unsigned short* h = (const unsigned short*)&v;
#pragma unroll
        for (int j = 0; j < 8; ++j) xs[w][base + j] = bf2f(h[j]);
    }
    __syncthreads();

    float sabs = 0.f;
#pragma unroll
    for (int i = 0; i < 32; ++i) sabs += fabsf(xs[w][lane + i * 64]);
#pragma unroll
    for (int d = 1; d < 64; d <<= 1) sabs += __shfl_xor(sabs, d, 64);

    const int L = lane;
    float bp = 0.f;
#pragma unroll
    for (int l = 0; l <= 5; ++l) {
        float v = xs[w][(1 << l) - 1 + (L >> (6 - l))];
        bp += ((L >> (5 - l)) & 1) ? fmaxf(v, 0.f) : fmaxf(-v, 0.f);
    }
    float p2[2], p4[4], p8[8], p16[16], p32[32];
    {
        float v = xs[w][63 + L];
        p2[0] = bp + fmaxf(-v, 0.f);
        p2[1] = bp + fmaxf(v, 0.f);
    }
#pragma unroll
    for (int c = 0; c < 2; ++c) {
        float v = xs[w][127 + 2 * L + c];
        p4[2 * c]     = p2[c] + fmaxf(-v, 0.f);
        p4[2 * c + 1] = p2[c] + fmaxf(v, 0.f);
    }
#pragma unroll
    for (int c = 0; c < 4; ++c) {
        float v = xs[w][255 + 4 * L + c];
        p8[2 * c]     = p4[c] + fmaxf(-v, 0.f);
        p8[2 * c + 1] = p4[c] + fmaxf(v, 0.f);
    }
#pragma unroll
    for (int c = 0; c < 8; ++c) {
        float v = xs[w][511 + 8 * L + c];
        p16[2 * c]     = p8[c] + fmaxf(-v, 0.f);
        p16[2 * c + 1] = p8[c] + fmaxf(v, 0.f);
    }
#pragma unroll
    for (int c = 0; c < 16; ++c) {
        float v = xs[w][1023 + 16 * L + c];
        p32[2 * c]     = p16[c] + fmaxf(-v, 0.f);
        p32[2 * c + 1] = p16[c] + fmaxf(v, 0.f);
    }

    float m[ODIM];
#pragma unroll
    for (int r = 0; r < ODIM; ++r) m[r] = 1e30f;
#pragma unroll
    for (int tt = 0; tt < 32; ++tt) m[tt % ODIM] = fminf(m[tt % ODIM], p32[tt]);

    int base_mod = (L * 32) % ODIM;
#pragma unroll
    for (int r = 0; r < ODIM; ++r) {
        int a = base_mod + r; if (a >= ODIM) a -= ODIM;
        cm[w][L][a] = m[r];
    }
    __syncthreads();

    if (lane < ODIM) {
        float mn = 1e30f;
        for (int l2 = 0; l2 < 64; ++l2) mn = fminf(mn, cm[w][l2][lane]);
        out[(size_t)row * ODIM + lane] = sabs - mn;
    }
}

extern "C" void kernel_launch(void* const* d_in, const int* in_sizes, int n_in,
                              void* d_out, int out_size, void* d_ws, size_t ws_size,
                              hipStream_t stream) {
    const float* in_x = (const float*)d_in[0];
    const float* W1   = (const float*)d_in[1];
    const float* b1   = (const float*)d_in[2];

    unsigned short* Abf = (unsigned short*)d_ws;                      // 16384*2048 bf16
    unsigned short* Wbf = Abf + (size_t)BATCH * K_DIM;                // 2048*2048 bf16
    unsigned short* Xbf = Wbf + (size_t)NPAD * K_DIM;                 // 16384*2048 bf16
    float* out = (float*)d_out;

    cvt_all<<<18432, 256, 0, stream>>>(in_x, W1, Abf, Wbf);
    gemm8<<<512, 512, 0, stream>>>(Abf, Wbf, b1, Xbf);
    tree_kernel<<<BATCH / 4, 256, 0, stream>>>(Xbf, out);
}